// Round 1
// baseline (92.787 us; speedup 1.0000x reference)
//
#include <hip/hip_runtime.h>
#include <math.h>

// Problem constants (fixed by setup_inputs)
constexpr int N   = 8192;
constexpr int D   = 128;
constexpr int IPC = 512;
constexpr int BZ  = 8192;
constexpr int Q0  = BZ - IPC;        // 7680: first query row
constexpr int NQ  = IPC;             // 512 queries
constexpr int JMAX = BZ - IPC;       // 7680 candidate columns [0, 7680)
constexpr int JCHUNK = 256;
constexpr int NCHUNK = JMAX / JCHUNK;        // 30
constexpr int EASY_CHUNKS = (2 * IPC) / JCHUNK; // 4 -> cols [0,1024) easy, rest hard
constexpr int QTILE = 16;
constexpr int NQT = NQ / QTILE;      // 32

// ---------------- K1: reciprocal norms of all rows ----------------
__global__ __launch_bounds__(256) void knorm(const float* __restrict__ f,
                                             float* __restrict__ rnorm) {
    int gwave = (blockIdx.x * blockDim.x + threadIdx.x) >> 6;  // one wave per row
    int lane  = threadIdx.x & 63;
    const float* row = f + (size_t)gwave * D;
    float x0 = row[lane];
    float x1 = row[lane + 64];
    float ss = x0 * x0 + x1 * x1;
    #pragma unroll
    for (int off = 32; off > 0; off >>= 1) ss += __shfl_xor(ss, off, 64);
    if (lane == 0) rnorm[gwave] = 1.0f / fmaxf(sqrtf(ss), 1e-12f);
}

// ---------------- K2: dots + per-(query,chunk) segmented max ----------------
// grid: (NCHUNK, NQT), block: 256 threads (4 waves).
// Wave w handles queries [qbase+4w, qbase+4w+4) over the whole 256-col chunk.
__global__ __launch_bounds__(256) void kdots(const float* __restrict__ f,
                                             const float* __restrict__ rnorm,
                                             float* __restrict__ pm) {
    constexpr int FT_STRIDE = JCHUNK + 4;  // 260 floats: rows 16B-aligned
    constexpr int QL_STRIDE = QTILE + 4;   // 20 floats: rows 16B-aligned
    __shared__ __align__(16) float Ft[32][FT_STRIDE];   // [k_local][j]   (33.3 KB)
    __shared__ __align__(16) float Ql[D * QL_STRIDE];   // [k][q]         (10.2 KB)

    const int tid   = threadIdx.x;
    const int chunk = blockIdx.x;          // 0..29
    const int qtb   = blockIdx.y;          // 0..31
    const int j0    = chunk * JCHUNK;
    const int qbase = Q0 + qtb * QTILE;

    // Stage query tile transposed: Ql[k][q]
    {
        int q  = tid >> 4;                 // 0..15
        int k0 = (tid & 15) * 8;           // 0,8,...,120
        const float* qrow = f + (size_t)(qbase + q) * D + k0;
        float4 v0 = *(const float4*)(qrow);
        float4 v1 = *(const float4*)(qrow + 4);
        Ql[(k0 + 0) * QL_STRIDE + q] = v0.x;
        Ql[(k0 + 1) * QL_STRIDE + q] = v0.y;
        Ql[(k0 + 2) * QL_STRIDE + q] = v0.z;
        Ql[(k0 + 3) * QL_STRIDE + q] = v0.w;
        Ql[(k0 + 4) * QL_STRIDE + q] = v1.x;
        Ql[(k0 + 5) * QL_STRIDE + q] = v1.y;
        Ql[(k0 + 6) * QL_STRIDE + q] = v1.z;
        Ql[(k0 + 7) * QL_STRIDE + q] = v1.w;
    }

    const int qg = tid >> 6;   // wave index: which 4-query group
    const int jg = tid & 63;   // lane: which 4-col group

    float acc[4][4] = {};

    for (int kc = 0; kc < D / 32; ++kc) {
        __syncthreads();  // protect Ft from previous iter's readers (and Ql 1st iter)
        // Stage F chunk transposed: Ft[k_local][j], coalesced 128B global segments
        {
            int rl = tid >> 3;            // 0..31
            int kl = (tid & 7) * 4;       // 0,4,...,28
            #pragma unroll
            for (int rr = 0; rr < 8; ++rr) {
                int row = rl + rr * 32;   // 0..255
                float4 v = *(const float4*)(f + (size_t)(j0 + row) * D + kc * 32 + kl);
                Ft[kl + 0][row] = v.x;
                Ft[kl + 1][row] = v.y;
                Ft[kl + 2][row] = v.z;
                Ft[kl + 3][row] = v.w;
            }
        }
        __syncthreads();

        const float* qp = &Ql[(kc * 32) * QL_STRIDE + qg * 4];
        const float* jp = &Ft[0][jg * 4];
        #pragma unroll
        for (int k = 0; k < 32; ++k) {
            float4 qv = *(const float4*)(qp + k * QL_STRIDE);  // broadcast within wave
            float4 jv = *(const float4*)(jp + k * FT_STRIDE);  // consecutive lanes -> consecutive addrs
            acc[0][0] = fmaf(qv.x, jv.x, acc[0][0]);
            acc[0][1] = fmaf(qv.x, jv.y, acc[0][1]);
            acc[0][2] = fmaf(qv.x, jv.z, acc[0][2]);
            acc[0][3] = fmaf(qv.x, jv.w, acc[0][3]);
            acc[1][0] = fmaf(qv.y, jv.x, acc[1][0]);
            acc[1][1] = fmaf(qv.y, jv.y, acc[1][1]);
            acc[1][2] = fmaf(qv.y, jv.z, acc[1][2]);
            acc[1][3] = fmaf(qv.y, jv.w, acc[1][3]);
            acc[2][0] = fmaf(qv.z, jv.x, acc[2][0]);
            acc[2][1] = fmaf(qv.z, jv.y, acc[2][1]);
            acc[2][2] = fmaf(qv.z, jv.z, acc[2][2]);
            acc[2][3] = fmaf(qv.z, jv.w, acc[2][3]);
            acc[3][0] = fmaf(qv.w, jv.x, acc[3][0]);
            acc[3][1] = fmaf(qv.w, jv.y, acc[3][1]);
            acc[3][2] = fmaf(qv.w, jv.z, acc[3][2]);
            acc[3][3] = fmaf(qv.w, jv.w, acc[3][3]);
        }
    }

    // Scale by reciprocal norms (strictly positive) and reduce max.
    float4 rj = *(const float4*)&rnorm[j0 + jg * 4];
    float m[4];
    #pragma unroll
    for (int a = 0; a < 4; ++a) {
        float mm = acc[a][0] * rj.x;
        mm = fmaxf(mm, acc[a][1] * rj.y);
        mm = fmaxf(mm, acc[a][2] * rj.z);
        mm = fmaxf(mm, acc[a][3] * rj.w);
        m[a] = mm * rnorm[qbase + qg * 4 + a];
    }
    #pragma unroll
    for (int off = 32; off > 0; off >>= 1) {
        #pragma unroll
        for (int a = 0; a < 4; ++a) m[a] = fmaxf(m[a], __shfl_xor(m[a], off, 64));
    }
    if (jg == 0) {
        #pragma unroll
        for (int a = 0; a < 4; ++a) {
            int qi = qtb * QTILE + qg * 4 + a;   // 0..511
            pm[qi * 32 + chunk] = m[a];
        }
    }
}

// ---------------- K3: final loss ----------------
__global__ __launch_bounds__(512) void kfinal(const float* __restrict__ pm,
                                              const float* __restrict__ a_in,
                                              float* __restrict__ out) {
    __shared__ float wsum[8];
    int q = threadIdx.x;  // 0..511
    float vce = -1e30f, vch = -1e30f;
    #pragma unroll
    for (int c = 0; c < EASY_CHUNKS; ++c) vce = fmaxf(vce, pm[q * 32 + c]);
    #pragma unroll
    for (int c = EASY_CHUNKS; c < NCHUNK; ++c) vch = fmaxf(vch, pm[q * 32 + c]);
    float d = (vch - vce) * 10.0f;  // /SIGMA1
    float p = (d > 0.0f) ? (d + log1pf(expf(-d))) : log1pf(expf(d));  // stable softplus
    #pragma unroll
    for (int off = 32; off > 0; off >>= 1) p += __shfl_xor(p, off, 64);
    int lane = q & 63, w = q >> 6;
    if (lane == 0) wsum[w] = p;
    __syncthreads();
    if (q == 0) {
        float s = 0.0f;
        #pragma unroll
        for (int i = 0; i < 8; ++i) s += wsum[i];
        out[0] = a_in[0] * (s / (float)NQ);
    }
}

extern "C" void kernel_launch(void* const* d_in, const int* in_sizes, int n_in,
                              void* d_out, int out_size, void* d_ws, size_t ws_size,
                              hipStream_t stream) {
    const float* f = (const float*)d_in[0];
    // d_in[1] = Lvec (unused by the reference computation)
    const float* a = (const float*)d_in[2];
    float* rnorm = (float*)d_ws;            // 8192 floats
    float* pm    = rnorm + N;               // 512*32 floats (30 used per row)
    float* out   = (float*)d_out;

    knorm<<<N * 64 / 256, 256, 0, stream>>>(f, rnorm);
    dim3 g2(NCHUNK, NQT);                   // 30 x 32 = 960 blocks
    kdots<<<g2, 256, 0, stream>>>(f, rnorm, pm);
    kfinal<<<1, 512, 0, stream>>>(pm, a, out);
}

// Round 2
// 77.184 us; speedup vs baseline: 1.2021x; 1.2021x over previous
//
#include <hip/hip_runtime.h>
#include <hip/hip_bf16.h>
#include <math.h>

// Problem constants (fixed by setup_inputs)
constexpr int N   = 8192;
constexpr int D   = 128;
constexpr int IPC = 512;
constexpr int BZ  = 8192;
constexpr int Q0  = BZ - IPC;        // 7680: first query row
constexpr int NQ  = IPC;             // 512 queries
constexpr int JMAX = BZ - IPC;       // 7680 candidate cols [0,7680)
constexpr int JBLK = 128;            // j per block
constexpr int NJB  = JMAX / JBLK;    // 60
constexpr int EASY_JB = (2 * IPC) / JBLK;  // 8 -> jblk 0..7 easy ([0,1024)), 8..59 hard
constexpr int QBLK = 64;             // q per block
constexpr int NQB  = NQ / QBLK;      // 8

typedef __attribute__((ext_vector_type(8))) short short8;   // 8 bf16 = 4 VGPRs
typedef __attribute__((ext_vector_type(4))) float f32x4;    // MFMA C/D

// ---------------- K1: normalize rows, emit bf16 ----------------
// One wave per row; lane handles elements 2*lane, 2*lane+1.
__global__ __launch_bounds__(256) void knorm(const float* __restrict__ f,
                                             __hip_bfloat16* __restrict__ fn) {
    int row  = (blockIdx.x * blockDim.x + threadIdx.x) >> 6;
    int lane = threadIdx.x & 63;
    const float* rp = f + (size_t)row * D;
    float2 v = *(const float2*)(rp + 2 * lane);
    float ss = v.x * v.x + v.y * v.y;
    #pragma unroll
    for (int off = 32; off > 0; off >>= 1) ss += __shfl_xor(ss, off, 64);
    float r = 1.0f / fmaxf(sqrtf(ss), 1e-12f);
    __hip_bfloat162 h;
    h.x = __float2bfloat16(v.x * r);
    h.y = __float2bfloat16(v.y * r);
    *(__hip_bfloat162*)(fn + (size_t)row * D + 2 * lane) = h;
}

// ---------------- K2: MFMA GEMM tile + segmented j-max ----------------
// grid (NJB, NQB), 256 threads = 4 waves. Block: 64 q x 128 j, K=128.
// Wave w owns j sub-range [jblk*128 + w*32, +32). All waves share the 64-q A tile.
// Fragments loaded directly from global (data is L2-resident, ~2 MB).
// A-op and B-op lane layouts are identical for 16x16x32: lane l holds row (l&15),
// k = (l>>4)*8 .. +7 -> row-major bf16 rows feed both operands, no LDS staging.
__global__ __launch_bounds__(256) void kgemm(const __hip_bfloat16* __restrict__ fnorm,
                                             float* __restrict__ pm) {
    __shared__ float red[4][QBLK];

    const int tid  = threadIdx.x;
    const int lane = tid & 63;
    const int wv   = tid >> 6;
    const int jblk = blockIdx.x;           // 0..59
    const int qblk = blockIdx.y;           // 0..7
    const int row16 = lane & 15;
    const int kgrp  = lane >> 4;           // 0..3

    const short* fn = (const short*)fnorm;
    const short* A  = fn + (size_t)(Q0 + qblk * QBLK) * D;           // 64 q rows
    const short* B  = fn + (size_t)(jblk * JBLK + wv * 32) * D;      // wave's 32 j rows

    f32x4 acc[4][2] = {};  // [q-group g][j-tile t]

    #pragma unroll
    for (int c = 0; c < 4; ++c) {          // k-chunks of 32
        const int ko = c * 32 + kgrp * 8;
        short8 a[4], b[2];
        #pragma unroll
        for (int g = 0; g < 4; ++g)
            a[g] = *(const short8*)(A + (g * 16 + row16) * D + ko);
        #pragma unroll
        for (int t = 0; t < 2; ++t)
            b[t] = *(const short8*)(B + (t * 16 + row16) * D + ko);
        #pragma unroll
        for (int g = 0; g < 4; ++g)
            #pragma unroll
            for (int t = 0; t < 2; ++t)
                acc[g][t] = __builtin_amdgcn_mfma_f32_16x16x32_bf16(a[g], b[t], acc[g][t], 0, 0, 0);
    }

    // C layout: lane holds j-col n=lane&15, q-row m=(lane>>4)*4+reg.
    // Max over j: combine the two j-tiles, then butterfly over low 4 lane bits.
    float vg[4][4];
    #pragma unroll
    for (int g = 0; g < 4; ++g)
        #pragma unroll
        for (int r = 0; r < 4; ++r)
            vg[g][r] = fmaxf(acc[g][0][r], acc[g][1][r]);
    #pragma unroll
    for (int off = 1; off < 16; off <<= 1)
        #pragma unroll
        for (int g = 0; g < 4; ++g)
            #pragma unroll
            for (int r = 0; r < 4; ++r)
                vg[g][r] = fmaxf(vg[g][r], __shfl_xor(vg[g][r], off, 64));

    if ((lane & 15) == 0) {
        int sub = lane >> 4;               // 0..3
        #pragma unroll
        for (int g = 0; g < 4; ++g)
            #pragma unroll
            for (int r = 0; r < 4; ++r)
                red[wv][g * 16 + sub * 4 + r] = vg[g][r];
    }
    __syncthreads();
    if (tid < QBLK) {
        float m = fmaxf(fmaxf(red[0][tid], red[1][tid]),
                        fmaxf(red[2][tid], red[3][tid]));
        pm[(size_t)(qblk * QBLK + tid) * NJB + jblk] = m;
    }
}

// ---------------- K3: final loss ----------------
__global__ __launch_bounds__(512) void kfinal(const float* __restrict__ pm,
                                              const float* __restrict__ a_in,
                                              float* __restrict__ out) {
    __shared__ float wsum[8];
    int q = threadIdx.x;  // 0..511
    const float* row = pm + (size_t)q * NJB;
    float vce = -1e30f, vch = -1e30f;
    #pragma unroll
    for (int c = 0; c < EASY_JB; ++c) vce = fmaxf(vce, row[c]);
    #pragma unroll
    for (int c = EASY_JB; c < NJB; ++c) vch = fmaxf(vch, row[c]);
    float d = (vch - vce) * 10.0f;  // /SIGMA1
    float p = (d > 0.0f) ? (d + log1pf(expf(-d))) : log1pf(expf(d));  // stable softplus
    #pragma unroll
    for (int off = 32; off > 0; off >>= 1) p += __shfl_xor(p, off, 64);
    int lane = q & 63, w = q >> 6;
    if (lane == 0) wsum[w] = p;
    __syncthreads();
    if (q == 0) {
        float s = 0.0f;
        #pragma unroll
        for (int i = 0; i < 8; ++i) s += wsum[i];
        out[0] = a_in[0] * (s / (float)NQ);
    }
}

extern "C" void kernel_launch(void* const* d_in, const int* in_sizes, int n_in,
                              void* d_out, int out_size, void* d_ws, size_t ws_size,
                              hipStream_t stream) {
    const float* f = (const float*)d_in[0];
    // d_in[1] = Lvec (unused by the reference computation)
    const float* a = (const float*)d_in[2];

    __hip_bfloat16* fn = (__hip_bfloat16*)d_ws;          // 8192*128 bf16 = 2 MB
    float* pm = (float*)((char*)d_ws + (size_t)N * D * sizeof(__hip_bfloat16)); // 512*60 f32
    float* out = (float*)d_out;

    knorm<<<N / 4, 256, 0, stream>>>(f, fn);             // 4 rows/block (4 waves)
    dim3 g2(NJB, NQB);                                   // 60 x 8 = 480 blocks
    kgemm<<<g2, 256, 0, stream>>>(fn, pm);
    kfinal<<<1, 512, 0, stream>>>(pm, a, out);
}

// Round 3
// 71.718 us; speedup vs baseline: 1.2938x; 1.0762x over previous
//
#include <hip/hip_runtime.h>
#include <hip/hip_bf16.h>
#include <math.h>

// Problem constants (fixed by setup_inputs)
constexpr int N   = 8192;
constexpr int D   = 128;
constexpr int IPC = 512;
constexpr int BZ  = 8192;
constexpr int Q0  = BZ - IPC;        // 7680: first query row
constexpr int NQ  = IPC;             // 512 queries
constexpr int JMAX = BZ - IPC;       // 7680 candidate cols [0,7680)
constexpr int JBLK = 128;            // j per block
constexpr int NJB  = JMAX / JBLK;    // 60
constexpr int EASY_JB = (2 * IPC) / JBLK;  // 8 -> jblk 0..7 easy ([0,1024)), 8..59 hard
constexpr int QBLK = 64;             // q per block
constexpr int NQB  = NQ / QBLK;      // 8
constexpr int RSTR = 136;            // LDS row stride in shorts (68 words = 4 mod 32 banks)

typedef __attribute__((ext_vector_type(8))) short short8;   // 8 bf16 = 4 VGPRs
typedef __attribute__((ext_vector_type(4))) float f32x4;    // MFMA C/D

// ---------------- K1: fused normalize (into LDS) + MFMA tile + segmented j-max ----------
// grid (NJB, NQB), 256 threads = 4 waves. Block computes 64 q x 128 j of the cosine
// matrix. Each block redundantly normalizes its own 64 A-rows + 128 B-rows from the
// fp32 input into bf16 LDS (47 MB aggregate re-read, L2-resident -> ~1.5 us total),
// which removes the separate knorm kernel + launch.
__global__ __launch_bounds__(256) void kmain(const float* __restrict__ f,
                                             float* __restrict__ pm) {
    __shared__ __align__(16) short S[192 * RSTR];   // rows 0..63 = A(q), 64..191 = B(j); 51 KB
    __shared__ float red[4][QBLK];

    const int tid  = threadIdx.x;
    const int lane = tid & 63;
    const int wv   = tid >> 6;
    const int jblk = blockIdx.x;           // 0..59
    const int qblk = blockIdx.y;           // 0..7

    // ---- Phase 1: normalize 192 rows -> bf16 LDS. 16 threads/row, 8 elems/thread.
    {
        const int sub = tid & 15;          // element group: elems [8*sub, 8*sub+8)
        const int rof = tid >> 4;          // row-within-group-of-16
        #pragma unroll
        for (int i = 0; i < 12; ++i) {
            int ridx = i * 16 + rof;       // 0..191
            int grow = (ridx < QBLK) ? (Q0 + qblk * QBLK + ridx)
                                     : (jblk * JBLK + (ridx - QBLK));
            const float* rp = f + (size_t)grow * D + sub * 8;
            float4 v0 = *(const float4*)(rp);
            float4 v1 = *(const float4*)(rp + 4);
            float ss = v0.x*v0.x + v0.y*v0.y + v0.z*v0.z + v0.w*v0.w
                     + v1.x*v1.x + v1.y*v1.y + v1.z*v1.z + v1.w*v1.w;
            // reduce across the 16 lanes sharing this row (lanes differ in low 4 bits)
            #pragma unroll
            for (int off = 1; off < 16; off <<= 1) ss += __shfl_xor(ss, off, 64);
            float r = 1.0f / fmaxf(sqrtf(ss), 1e-12f);
            float sc[8] = { v0.x*r, v0.y*r, v0.z*r, v0.w*r,
                            v1.x*r, v1.y*r, v1.z*r, v1.w*r };
            short8 h;
            #pragma unroll
            for (int e = 0; e < 8; ++e) {
                __hip_bfloat16 b = __float2bfloat16(sc[e]);
                h[e] = *(short*)&b;
            }
            *(short8*)&S[ridx * RSTR + sub * 8] = h;
        }
    }
    __syncthreads();

    // ---- Phase 2: MFMA. Wave wv owns j sub-range [wv*32, wv*32+32).
    // 16x16x32 operand layout: lane l holds row (l&15), k = (l>>4)*8..+7.
    const int row16 = lane & 15;
    const int kgrp  = lane >> 4;           // 0..3
    const short* As = S;
    const short* Bs = S + QBLK * RSTR + wv * 32 * RSTR;

    f32x4 acc[4][2] = {};  // [q-group g][j-tile t]
    #pragma unroll
    for (int c = 0; c < 4; ++c) {          // k-chunks of 32
        const int ko = c * 32 + kgrp * 8;
        short8 a[4], b[2];
        #pragma unroll
        for (int g = 0; g < 4; ++g)
            a[g] = *(const short8*)(As + (g * 16 + row16) * RSTR + ko);
        #pragma unroll
        for (int t = 0; t < 2; ++t)
            b[t] = *(const short8*)(Bs + (t * 16 + row16) * RSTR + ko);
        #pragma unroll
        for (int g = 0; g < 4; ++g)
            #pragma unroll
            for (int t = 0; t < 2; ++t)
                acc[g][t] = __builtin_amdgcn_mfma_f32_16x16x32_bf16(a[g], b[t], acc[g][t], 0, 0, 0);
    }

    // ---- Phase 3: j-max. C layout: lane holds j-col n=lane&15, q-row m=(lane>>4)*4+reg.
    float vg[4][4];
    #pragma unroll
    for (int g = 0; g < 4; ++g)
        #pragma unroll
        for (int r = 0; r < 4; ++r)
            vg[g][r] = fmaxf(acc[g][0][r], acc[g][1][r]);
    #pragma unroll
    for (int off = 1; off < 16; off <<= 1)
        #pragma unroll
        for (int g = 0; g < 4; ++g)
            #pragma unroll
            for (int r = 0; r < 4; ++r)
                vg[g][r] = fmaxf(vg[g][r], __shfl_xor(vg[g][r], off, 64));

    if ((lane & 15) == 0) {
        int sgrp = lane >> 4;              // 0..3
        #pragma unroll
        for (int g = 0; g < 4; ++g)
            #pragma unroll
            for (int r = 0; r < 4; ++r)
                red[wv][g * 16 + sgrp * 4 + r] = vg[g][r];
    }
    __syncthreads();
    if (tid < QBLK) {
        float m = fmaxf(fmaxf(red[0][tid], red[1][tid]),
                        fmaxf(red[2][tid], red[3][tid]));
        pm[(size_t)(qblk * QBLK + tid) * NJB + jblk] = m;
    }
}

// ---------------- K2: final loss ----------------
__global__ __launch_bounds__(512) void kfinal(const float* __restrict__ pm,
                                              const float* __restrict__ a_in,
                                              float* __restrict__ out) {
    __shared__ float wsum[8];
    int q = threadIdx.x;  // 0..511
    const float* row = pm + (size_t)q * NJB;
    float vce = -1e30f, vch = -1e30f;
    #pragma unroll
    for (int c = 0; c < EASY_JB; ++c) vce = fmaxf(vce, row[c]);
    #pragma unroll
    for (int c = EASY_JB; c < NJB; ++c) vch = fmaxf(vch, row[c]);
    float d = (vch - vce) * 10.0f;  // /SIGMA1
    float p = (d > 0.0f) ? (d + log1pf(expf(-d))) : log1pf(expf(d));  // stable softplus
    #pragma unroll
    for (int off = 32; off > 0; off >>= 1) p += __shfl_xor(p, off, 64);
    int lane = q & 63, w = q >> 6;
    if (lane == 0) wsum[w] = p;
    __syncthreads();
    if (q == 0) {
        float s = 0.0f;
        #pragma unroll
        for (int i = 0; i < 8; ++i) s += wsum[i];
        out[0] = a_in[0] * (s / (float)NQ);
    }
}

extern "C" void kernel_launch(void* const* d_in, const int* in_sizes, int n_in,
                              void* d_out, int out_size, void* d_ws, size_t ws_size,
                              hipStream_t stream) {
    const float* f = (const float*)d_in[0];
    // d_in[1] = Lvec (unused by the reference computation)
    const float* a = (const float*)d_in[2];

    float* pm  = (float*)d_ws;             // 512*60 f32
    float* out = (float*)d_out;

    dim3 g(NJB, NQB);                      // 60 x 8 = 480 blocks
    kmain<<<g, 256, 0, stream>>>(f, pm);
    kfinal<<<1, 512, 0, stream>>>(pm, a, out);
}